// Round 1
// baseline (201.377 us; speedup 1.0000x reference)
//
#include <hip/hip_runtime.h>
#include <hip/hip_bf16.h>

// Elementwise over B=8388608 rows of X:(B,4) f32 -> out:(B,2) f32.
// Memory-bound: 128 MiB in + 64 MiB out. One thread per row, float4 load,
// float2 store, all perfectly coalesced.

__global__ __launch_bounds__(256) void cgp_kernel(const float4* __restrict__ X,
                                                  const float* __restrict__ ephs,
                                                  float2* __restrict__ out,
                                                  int B) {
    int i = blockIdx.x * blockDim.x + threadIdx.x;
    if (i >= B) return;

    const float c0 = ephs[0];
    const float c1 = ephs[1];

    float4 x = X[i];  // x0,x1,x2,x3 contiguous per row -> 16B/lane coalesced

    float n4 = x.x * x.y;
    float n5 = __sinf(0.0f);  // placeholder avoided; use precise path below
    n5 = sinf(n4 + c0);
    float n6 = x.z * x.w;
    float n7 = fmaf(n5, n6, sinf(x.z));
    float n8 = fmaf(cosf(n7), c1, x.x);

    out[i] = make_float2(n7, n8);
}

extern "C" void kernel_launch(void* const* d_in, const int* in_sizes, int n_in,
                              void* d_out, int out_size, void* d_ws, size_t ws_size,
                              hipStream_t stream) {
    const float4* X  = (const float4*)d_in[0];
    const float* eph = (const float*)d_in[1];
    float2* out      = (float2*)d_out;
    int B = in_sizes[0] / 4;  // 8388608

    int block = 256;
    int grid = (B + block - 1) / block;  // 32768 blocks
    cgp_kernel<<<grid, block, 0, stream>>>(X, eph, out, B);
}